// Round 2
// baseline (551.135 us; speedup 1.0000x reference)
//
#include <hip/hip_runtime.h>
#include <math.h>

// Problem constants
#define Bn   32
#define Cn   684
#define Hn   16
#define Wn   64
#define HWn  1024
#define HIDn 256
#define An   512
#define KKn  121           // 11*11
#define CREAL 805          // 684 + 121
#define CPAD 832           // padded to 26 chunks of 32

// Output layout (flat fp32): context [32,684]=21888 | alpha [32,1024]=32768 | alpha_sum_new = 32768
#define OUT_ALPHA 21888
#define OUT_ASUM  (21888 + 32768)

// ---------------------------------------------------------------------------
// K0: query[b,a] = bh[a] + bec[a] + sum_h hidden[b,h]*Wh[a,h]
//     (bec folded in: both are added before tanh per-a)
__global__ __launch_bounds__(256) void k_query(
    const float* __restrict__ hidden,
    const float* __restrict__ Wh,
    const float* __restrict__ bh,
    const float* __restrict__ bec,
    float* __restrict__ query)
{
    __shared__ float hs[HIDn];
    const int b = blockIdx.x, t = threadIdx.x;
    if (t < HIDn) hs[t] = hidden[b * HIDn + t];
    __syncthreads();
    for (int a = t; a < An; a += 256) {
        const float4* wp = (const float4*)(Wh + (size_t)a * HIDn);
        float s = bh[a] + bec[a];
        #pragma unroll 8
        for (int i = 0; i < HIDn / 4; ++i) {
            float4 w = wp[i];
            s = fmaf(hs[4 * i],     w.x, s);
            s = fmaf(hs[4 * i + 1], w.y, s);
            s = fmaf(hs[4 * i + 2], w.z, s);
            s = fmaf(hs[4 * i + 3], w.w, s);
        }
        query[b * An + a] = s;
    }
}

// ---------------------------------------------------------------------------
// K1: build VT [832 c'][512 a] fp32:
//   rows 0..683   = Wec[a][c']            (1x1 conv weights)
//   rows 684..804 = Wfused[a][ij] = sum_k Waw[a,k]*Wac[k,ij]  (conv+proj fused)
//   rows 805..831 = 0
__global__ __launch_bounds__(128) void k_build_vt(
    const float* __restrict__ Wec,
    const float* __restrict__ Wac,
    const float* __restrict__ Waw,
    float* __restrict__ VT)
{
    __shared__ float waw_s[512];
    const int a = blockIdx.x, t = threadIdx.x;
    for (int i = t; i < 512; i += 128) waw_s[i] = Waw[(size_t)a * 512 + i];
    __syncthreads();
    for (int cp = t; cp < Cn; cp += 128)
        VT[(size_t)cp * An + a] = Wec[(size_t)a * Cn + cp];
    if (t < KKn) {
        float s = 0.f;
        for (int k = 0; k < 512; ++k)
            s = fmaf(waw_s[k], Wac[k * KKn + t], s);
        VT[(size_t)(Cn + t) * An + a] = s;
    }
    for (int cp = CREAL + t; cp < CPAD; cp += 128)
        VT[(size_t)cp * An + a] = 0.f;
}

// ---------------------------------------------------------------------------
// K2: fused energy GEMM. Block = (a-chunk of 128) x (one (b,h) row: 64 pos).
// s[pos][a] = sum_{c'} U[c'][pos] * VT[c'][a]; U rows: X | im2col(alpha) | 0
// energy[b,hw] += sum_a Wv[a]*tanh(s + query[b,a])   (atomic over 4 a-chunks)
__global__ __launch_bounds__(256) void k_energy(
    const float* __restrict__ X,
    const float* __restrict__ asum,
    const float* __restrict__ Wv,
    const float* __restrict__ query,
    const float* __restrict__ VT,
    float* __restrict__ energy)
{
    __shared__ float plane[26 * 74];   // padded alpha_sum plane (+5 border)
    __shared__ float Us[32 * 64];      // U chunk  [32 c'][64 pos]
    __shared__ float Ws[32 * 128];     // VT chunk [32 c'][128 a]
    __shared__ float red[16 * 64];     // epilogue reduction

    const int t = threadIdx.x;
    const int ac = blockIdx.x, hh = blockIdx.y, b = blockIdx.z;
    const int a0 = ac * 128;

    // stage padded alpha plane (zeros outside image)
    for (int i = t; i < 26 * 74; i += 256) {
        int r = i / 74, c = i - r * 74;
        int hr = r - 5, wc = c - 5;
        float v = 0.f;
        if (hr >= 0 && hr < Hn && wc >= 0 && wc < Wn)
            v = asum[b * HWn + hr * Wn + wc];
        plane[i] = v;
    }

    const int tp = t & 15, ta = t >> 4;          // thread tile: 4 pos x 8 a
    float acc[4][8];
    #pragma unroll
    for (int i = 0; i < 4; ++i)
        #pragma unroll
        for (int j = 0; j < 8; ++j) acc[i][j] = 0.f;

    const int r_us = t >> 3, pseg = (t & 7) * 8;   // Us staging map
    const int cc_ws = t >> 3, aseg = (t & 7) * 16; // Ws staging map

    for (int ch = 0; ch < 26; ++ch) {
        const int c0 = ch * 32;
        __syncthreads();
        // ---- stage Us [32][64]
        {
            int row = c0 + r_us;
            float v[8];
            if (row < Cn) {
                const float* xr =
                    X + ((size_t)(b * Cn + row)) * HWn + hh * Wn + pseg;
                float4 q0 = *(const float4*)xr;
                float4 q1 = *(const float4*)(xr + 4);
                v[0] = q0.x; v[1] = q0.y; v[2] = q0.z; v[3] = q0.w;
                v[4] = q1.x; v[5] = q1.y; v[6] = q1.z; v[7] = q1.w;
            } else if (row < CREAL) {
                int ij = row - Cn; int di = ij / 11, dj = ij - di * 11;
                const float* pr = &plane[(hh + di) * 74 + dj + pseg];
                #pragma unroll
                for (int j = 0; j < 8; ++j) v[j] = pr[j];
            } else {
                #pragma unroll
                for (int j = 0; j < 8; ++j) v[j] = 0.f;
            }
            #pragma unroll
            for (int j = 0; j < 8; ++j) Us[r_us * 64 + pseg + j] = v[j];
        }
        // ---- stage Ws [32][128]
        {
            const float* vp = VT + (size_t)(c0 + cc_ws) * An + a0 + aseg;
            float4 w0 = *(const float4*)(vp);
            float4 w1 = *(const float4*)(vp + 4);
            float4 w2 = *(const float4*)(vp + 8);
            float4 w3 = *(const float4*)(vp + 12);
            float* wd = &Ws[cc_ws * 128 + aseg];
            *(float4*)(wd)      = w0; *(float4*)(wd + 4)  = w1;
            *(float4*)(wd + 8)  = w2; *(float4*)(wd + 12) = w3;
        }
        __syncthreads();
        // ---- outer-product inner loop
        #pragma unroll 8
        for (int cc = 0; cc < 32; ++cc) {
            float4 x4 = *(const float4*)&Us[cc * 64 + tp * 4];
            float4 wa = *(const float4*)&Ws[cc * 128 + ta * 8];
            float4 wb = *(const float4*)&Ws[cc * 128 + ta * 8 + 4];
            float xs[4] = {x4.x, x4.y, x4.z, x4.w};
            float wv[8] = {wa.x, wa.y, wa.z, wa.w, wb.x, wb.y, wb.z, wb.w};
            #pragma unroll
            for (int p = 0; p < 4; ++p)
                #pragma unroll
                for (int a = 0; a < 8; ++a)
                    acc[p][a] = fmaf(xs[p], wv[a], acc[p][a]);
        }
    }

    // ---- epilogue: tanh + Wv, reduce over a
    float e[4] = {0.f, 0.f, 0.f, 0.f};
    #pragma unroll
    for (int ai = 0; ai < 8; ++ai) {
        int a = a0 + ta * 8 + ai;
        float q  = query[b * An + a];
        float wv = Wv[a];
        #pragma unroll
        for (int p = 0; p < 4; ++p)
            e[p] += wv * tanhf(acc[p][ai] + q);
    }
    __syncthreads();
    #pragma unroll
    for (int p = 0; p < 4; ++p) red[ta * 64 + tp * 4 + p] = e[p];
    __syncthreads();
    if (t < 64) {
        float s = 0.f;
        #pragma unroll
        for (int i = 0; i < 16; ++i) s += red[i * 64 + t];
        atomicAdd(&energy[b * HWn + hh * Wn + t], s);
    }
}

// ---------------------------------------------------------------------------
// K3: global max of energy (bv cancels in softmax)
__global__ __launch_bounds__(1024) void k_max(
    const float* __restrict__ energy, float* __restrict__ emax)
{
    __shared__ float wm[16];
    const int t = threadIdx.x;
    float m = -1e30f;
    for (int i = t; i < Bn * HWn; i += 1024) m = fmaxf(m, energy[i]);
    for (int off = 32; off >= 1; off >>= 1) m = fmaxf(m, __shfl_down(m, off, 64));
    if ((t & 63) == 0) wm[t >> 6] = m;
    __syncthreads();
    if (t == 0) {
        float mm = wm[0];
        for (int i = 1; i < 16; ++i) mm = fmaxf(mm, wm[i]);
        emax[0] = mm;
    }
}

// ---------------------------------------------------------------------------
// K4: per-batch softmax -> alpha (fp32 ws + fp32 out) and alpha_sum_new
__global__ __launch_bounds__(1024) void k_softmax(
    const float* __restrict__ energy, const float* __restrict__ emax,
    const float* __restrict__ mask, const float* __restrict__ asum,
    float* __restrict__ alpha_f, float* __restrict__ out)
{
    __shared__ float sm[17];
    const int b = blockIdx.x, t = threadIdx.x;
    float ex = expf(energy[b * HWn + t] - emax[0]) * mask[b * HWn + t];
    float s = ex;
    for (int off = 32; off >= 1; off >>= 1) s += __shfl_down(s, off, 64);
    if ((t & 63) == 0) sm[t >> 6] = s;
    __syncthreads();
    if (t == 0) {
        float tot = 0.f;
        for (int i = 0; i < 16; ++i) tot += sm[i];
        sm[16] = tot + 1e-10f;
    }
    __syncthreads();
    float alpha = ex / sm[16];
    alpha_f[b * HWn + t] = alpha;
    out[OUT_ALPHA + b * HWn + t] = alpha;
    out[OUT_ASUM  + b * HWn + t] = alpha + asum[b * HWn + t];
}

// ---------------------------------------------------------------------------
// K5: context[b,c] = sum_hw alpha[b,hw]*X[b,c,hw]; one wave per c
__global__ __launch_bounds__(256) void k_context(
    const float* __restrict__ X, const float* __restrict__ alpha_f,
    float* __restrict__ out)
{
    const int t = threadIdx.x, lane = t & 63, wid = t >> 6;
    const int b = blockIdx.y;
    const int c = blockIdx.x * 4 + wid;
    const float* xp = X + ((size_t)(b * Cn + c)) * HWn;
    const float* ap = alpha_f + b * HWn;
    float s = 0.f;
    #pragma unroll
    for (int i = 0; i < 4; ++i) {
        int off = i * 256 + lane * 4;
        float4 x = *(const float4*)(xp + off);
        float4 a = *(const float4*)(ap + off);
        s = fmaf(a.x, x.x, s);
        s = fmaf(a.y, x.y, s);
        s = fmaf(a.z, x.z, s);
        s = fmaf(a.w, x.w, s);
    }
    for (int off = 32; off >= 1; off >>= 1) s += __shfl_down(s, off, 64);
    if (lane == 0) out[b * Cn + c] = s;
}

// ---------------------------------------------------------------------------
extern "C" void kernel_launch(void* const* d_in, const int* in_sizes, int n_in,
                              void* d_out, int out_size, void* d_ws, size_t ws_size,
                              hipStream_t stream)
{
    const float* X      = (const float*)d_in[0];
    const float* hidden = (const float*)d_in[1];
    const float* asum   = (const float*)d_in[2];
    const float* mask   = (const float*)d_in[3];
    const float* Wh     = (const float*)d_in[4];
    const float* bh     = (const float*)d_in[5];
    const float* Wec    = (const float*)d_in[6];
    const float* bec    = (const float*)d_in[7];
    const float* Wac    = (const float*)d_in[8];
    const float* Waw    = (const float*)d_in[9];
    const float* Wv     = (const float*)d_in[10];
    (void)in_sizes; (void)n_in; (void)out_size; (void)ws_size;

    float* out = (float*)d_out;
    float* ws = (float*)d_ws;
    float* query   = ws;                          // 16384
    float* VT      = ws + 16384;                  // 425984
    float* energy  = ws + 16384 + 425984;         // 32768
    float* emax    = energy + 32768;              // 8 (padded)
    float* alpha_f = emax + 8;                    // 32768

    hipMemsetAsync(energy, 0, 32768 * sizeof(float), stream);
    k_query  <<<dim3(32),        dim3(256),  0, stream>>>(hidden, Wh, bh, bec, query);
    k_build_vt<<<dim3(512),      dim3(128),  0, stream>>>(Wec, Wac, Waw, VT);
    k_energy <<<dim3(4, 16, 32), dim3(256),  0, stream>>>(X, asum, Wv, query, VT, energy);
    k_max    <<<dim3(1),         dim3(1024), 0, stream>>>(energy, emax);
    k_softmax<<<dim3(32),        dim3(1024), 0, stream>>>(energy, emax, mask, asum, alpha_f, out);
    k_context<<<dim3(171, 32),   dim3(256),  0, stream>>>(X, alpha_f, out);
}

// Round 3
// 258.089 us; speedup vs baseline: 2.1354x; 2.1354x over previous
//
#include <hip/hip_runtime.h>
#include <math.h>

// Problem constants
#define Bn   32
#define Cn   684
#define Hn   16
#define Wn   64
#define HWn  1024
#define HIDn 256
#define An   512
#define KKn  121           // 11*11
#define CREAL 805          // 684 + 121
#define CPAD 832           // 26 chunks of 32
#define NSTEP 26

// Output layout (flat fp32): context [32,684] | alpha [32,1024] | alpha_sum_new [32,1024]
#define OUT_ALPHA 21888
#define OUT_ASUM  (21888 + 32768)

typedef short short8 __attribute__((ext_vector_type(8)));     // 8 bf16 = 4 VGPRs
typedef float floatx4 __attribute__((ext_vector_type(4)));    // MFMA acc

__device__ __forceinline__ unsigned short f2bf(float f) {
    union { float f; unsigned int i; } v; v.f = f;
    unsigned int i = v.i;
    return (unsigned short)((i + 0x7fffu + ((i >> 16) & 1u)) >> 16);
}

// async global->LDS, 16B per lane; lds base must be wave-uniform
__device__ __forceinline__ void async_lds16(void* lds, const void* g) {
    __builtin_amdgcn_global_load_lds(
        (const __attribute__((address_space(1))) unsigned int*)g,
        (__attribute__((address_space(3))) unsigned int*)lds, 16, 0, 0);
}

// ---------------------------------------------------------------------------
// K0: query[b,a] = bh[a] + bec[a] + sum_h hidden[b,h]*Wh[a,h]
__global__ __launch_bounds__(256) void k_query(
    const float* __restrict__ hidden,
    const float* __restrict__ Wh,
    const float* __restrict__ bh,
    const float* __restrict__ bec,
    float* __restrict__ query)
{
    __shared__ float hs[HIDn];
    const int b = blockIdx.x, t = threadIdx.x;
    if (t < HIDn) hs[t] = hidden[b * HIDn + t];
    __syncthreads();
    for (int a = t; a < An; a += 256) {
        const float4* wp = (const float4*)(Wh + (size_t)a * HIDn);
        float s = bh[a] + bec[a];
        #pragma unroll 8
        for (int i = 0; i < HIDn / 4; ++i) {
            float4 w = wp[i];
            s = fmaf(hs[4 * i],     w.x, s);
            s = fmaf(hs[4 * i + 1], w.y, s);
            s = fmaf(hs[4 * i + 2], w.z, s);
            s = fmaf(hs[4 * i + 3], w.w, s);
        }
        query[b * An + a] = s;
    }
}

// ---------------------------------------------------------------------------
// K1: build VTbf [512 a][832 c'] bf16 (a-major, k-contiguous for MFMA B-frags)
//   c' 0..683   = Wec[a][c]
//   c' 684..804 = Wfused[a][ij] = sum_k Waw[a,k]*Wac[k,ij]
//   c' 805..831 = 0
__global__ __launch_bounds__(128) void k_build_vt(
    const float* __restrict__ Wec,
    const float* __restrict__ Wac,
    const float* __restrict__ Waw,
    unsigned short* __restrict__ VTbf)
{
    __shared__ float waw_s[512];
    const int a = blockIdx.x, t = threadIdx.x;
    for (int i = t; i < 512; i += 128) waw_s[i] = Waw[(size_t)a * 512 + i];
    __syncthreads();
    for (int cp = t; cp < Cn; cp += 128)
        VTbf[(size_t)a * CPAD + cp] = f2bf(Wec[(size_t)a * Cn + cp]);
    if (t < KKn) {
        float s = 0.f;
        #pragma unroll 8
        for (int k = 0; k < 512; ++k)
            s = fmaf(waw_s[k], Wac[k * KKn + t], s);
        VTbf[(size_t)a * CPAD + Cn + t] = f2bf(s);
    }
    for (int cp = CREAL + t; cp < CPAD; cp += 128)
        VTbf[(size_t)a * CPAD + cp] = 0;
}

// ---------------------------------------------------------------------------
// K2: MFMA energy kernel. Block = one (b,h) row: 64 pos x 512 a x 832 c'.
__device__ __forceinline__ float fetchU(const float* __restrict__ X,
                                        const float* plane,
                                        int b, int hh, int m, int row) {
    if (row < Cn)   return X[((size_t)(b * Cn + row)) * HWn + hh * Wn + m];
    if (row < CREAL) {
        int ij = row - Cn; int di = ij / 11, dj = ij - di * 11;
        return plane[di * 74 + m + dj];
    }
    return 0.f;
}

__global__ __launch_bounds__(256, 2) void k_energy(
    const float* __restrict__ X,
    const float* __restrict__ asum,
    const float* __restrict__ Wv,
    const float* __restrict__ query,
    const unsigned short* __restrict__ VTbf,
    float* __restrict__ energy)
{
    __shared__ unsigned short As[64 * 40];   // A tile [m][k], stride 40 (pad)
    __shared__ unsigned short Bs[512 * 32];  // B tile [n][k], XOR-swizzled chunks; reused as red
    __shared__ float plane[11 * 74];         // padded alpha rows hh-5..hh+5
    __shared__ float qs[512];
    __shared__ float wvs[512];

    const int t = threadIdx.x;
    const int hh = blockIdx.x, b = blockIdx.y;
    const int w = t >> 6, lane = t & 63;
    const int q = lane >> 4, r = lane & 15;

    // stage plane / query / Wv
    for (int i = t; i < 11 * 74; i += 256) {
        int di = i / 74, cc = i - di * 74;
        int h2 = hh + di - 5, w2 = cc - 5;
        float v = 0.f;
        if (h2 >= 0 && h2 < Hn && w2 >= 0 && w2 < Wn) v = asum[b * HWn + h2 * Wn + w2];
        plane[i] = v;
    }
    qs[t]        = query[b * An + t];
    qs[t + 256]  = query[b * An + t + 256];
    wvs[t]       = Wv[t];
    wvs[t + 256] = Wv[t + 256];

    floatx4 acc[4][8];
    #pragma unroll
    for (int mf = 0; mf < 4; ++mf)
        #pragma unroll
        for (int nf = 0; nf < 8; ++nf)
            acc[mf][nf] = (floatx4){0.f, 0.f, 0.f, 0.f};

    for (int ch = 0; ch < NSTEP; ++ch) {
        const int c0 = ch * 32;
        __syncthreads();
        // ---- stage A: thread covers (m=lane, k = w*8..w*8+7); coalesced dword
        //      loads along pos, RNE-pack to bf16, one ds_write_b128
        {
            unsigned int pk[4];
            #pragma unroll
            for (int jj = 0; jj < 4; ++jj) {
                int r0 = c0 + w * 8 + jj * 2;
                float v0 = fetchU(X, plane, b, hh, lane, r0);
                float v1 = fetchU(X, plane, b, hh, lane, r0 + 1);
                unsigned int u0 = __float_as_uint(v0), u1 = __float_as_uint(v1);
                u0 = (u0 + 0x7fffu + ((u0 >> 16) & 1u)) >> 16;
                u1 = (u1 + 0x7fffu + ((u1 >> 16) & 1u)) & 0xffff0000u;
                pk[jj] = u0 | u1;
            }
            uint4* dst = (uint4*)&As[lane * 40 + w * 8];
            *dst = make_uint4(pk[0], pk[1], pk[2], pk[3]);
        }
        // ---- stage B: async DMA, XOR swizzle on the GLOBAL side
        #pragma unroll
        for (int ii = 0; ii < 8; ++ii) {
            int n0 = w * 128 + ii * 16;
            int rowB = n0 + (lane >> 2);
            int gc = (lane & 3) ^ ((lane >> 2) & 3);
            const unsigned short* gB = VTbf + (size_t)rowB * CPAD + c0 + gc * 8;
            async_lds16(&Bs[n0 * 32], gB);
        }
        __syncthreads();
        // ---- fragments + 32 MFMA
        short8 af[4], bfr[8];
        #pragma unroll
        for (int mf = 0; mf < 4; ++mf)
            af[mf] = *(const short8*)&As[(mf * 16 + r) * 40 + q * 8];
        #pragma unroll
        for (int nf = 0; nf < 8; ++nf) {
            int rowB = w * 128 + nf * 16 + r;
            bfr[nf] = *(const short8*)&Bs[rowB * 32 + (q ^ (r & 3)) * 8];
        }
        #pragma unroll
        for (int mf = 0; mf < 4; ++mf)
            #pragma unroll
            for (int nf = 0; nf < 8; ++nf)
                acc[mf][nf] = __builtin_amdgcn_mfma_f32_16x16x32_bf16(
                    af[mf], bfr[nf], acc[mf][nf], 0, 0, 0);
    }

    // ---- epilogue: e[m] = sum_n Wv[n]*tanh(acc + query[n])
    float ep[16];
    #pragma unroll
    for (int i = 0; i < 16; ++i) ep[i] = 0.f;
    #pragma unroll
    for (int nf = 0; nf < 8; ++nf) {
        int n = w * 128 + nf * 16 + r;
        float qv = qs[n], wv = wvs[n];
        #pragma unroll
        for (int mf = 0; mf < 4; ++mf)
            #pragma unroll
            for (int rg = 0; rg < 4; ++rg) {
                float x = acc[mf][nf][rg] + qv;
                float e2 = __expf(2.f * x);                       // inf-safe
                float th = 1.f - 2.f * __builtin_amdgcn_rcpf(e2 + 1.f);
                ep[mf * 4 + rg] += wv * th;
            }
    }
    __syncthreads();
    float* red = (float*)Bs;   // 64 x 65 floats = 16.6 KB, fits in Bs
    #pragma unroll
    for (int mf = 0; mf < 4; ++mf)
        #pragma unroll
        for (int rg = 0; rg < 4; ++rg)
            red[(mf * 16 + q * 4 + rg) * 65 + w * 16 + r] = ep[mf * 4 + rg];
    __syncthreads();
    if (t < 64) {
        float s = 0.f;
        #pragma unroll 16
        for (int i = 0; i < 64; ++i) s += red[t * 65 + i];
        energy[b * HWn + hh * Wn + t] = s;
    }
}

// ---------------------------------------------------------------------------
// K3: global max of energy
__global__ __launch_bounds__(1024) void k_max(
    const float* __restrict__ energy, float* __restrict__ emax)
{
    __shared__ float wm[16];
    const int t = threadIdx.x;
    float m = -1e30f;
    for (int i = t; i < Bn * HWn; i += 1024) m = fmaxf(m, energy[i]);
    for (int off = 32; off >= 1; off >>= 1) m = fmaxf(m, __shfl_down(m, off, 64));
    if ((t & 63) == 0) wm[t >> 6] = m;
    __syncthreads();
    if (t == 0) {
        float mm = wm[0];
        for (int i = 1; i < 16; ++i) mm = fmaxf(mm, wm[i]);
        emax[0] = mm;
    }
}

// ---------------------------------------------------------------------------
// K4: per-batch softmax -> alpha, alpha_sum_new
__global__ __launch_bounds__(1024) void k_softmax(
    const float* __restrict__ energy, const float* __restrict__ emax,
    const float* __restrict__ mask, const float* __restrict__ asum,
    float* __restrict__ alpha_f, float* __restrict__ out)
{
    __shared__ float sm[17];
    const int b = blockIdx.x, t = threadIdx.x;
    float ex = expf(energy[b * HWn + t] - emax[0]) * mask[b * HWn + t];
    float s = ex;
    for (int off = 32; off >= 1; off >>= 1) s += __shfl_down(s, off, 64);
    if ((t & 63) == 0) sm[t >> 6] = s;
    __syncthreads();
    if (t == 0) {
        float tot = 0.f;
        for (int i = 0; i < 16; ++i) tot += sm[i];
        sm[16] = tot + 1e-10f;
    }
    __syncthreads();
    float alpha = ex / sm[16];
    alpha_f[b * HWn + t] = alpha;
    out[OUT_ALPHA + b * HWn + t] = alpha;
    out[OUT_ASUM  + b * HWn + t] = alpha + asum[b * HWn + t];
}

// ---------------------------------------------------------------------------
// K5: context[b,c] = sum_hw alpha[b,hw]*X[b,c,hw]; one wave per c
__global__ __launch_bounds__(256) void k_context(
    const float* __restrict__ X, const float* __restrict__ alpha_f,
    float* __restrict__ out)
{
    const int t = threadIdx.x, lane = t & 63, wid = t >> 6;
    const int b = blockIdx.y;
    const int c = blockIdx.x * 4 + wid;
    const float* xp = X + ((size_t)(b * Cn + c)) * HWn;
    const float* ap = alpha_f + b * HWn;
    float s = 0.f;
    #pragma unroll
    for (int i = 0; i < 4; ++i) {
        int off = i * 256 + lane * 4;
        float4 x = *(const float4*)(xp + off);
        float4 a = *(const float4*)(ap + off);
        s = fmaf(a.x, x.x, s);
        s = fmaf(a.y, x.y, s);
        s = fmaf(a.z, x.z, s);
        s = fmaf(a.w, x.w, s);
    }
    for (int off = 32; off >= 1; off >>= 1) s += __shfl_down(s, off, 64);
    if (lane == 0) out[b * Cn + c] = s;
}

// ---------------------------------------------------------------------------
extern "C" void kernel_launch(void* const* d_in, const int* in_sizes, int n_in,
                              void* d_out, int out_size, void* d_ws, size_t ws_size,
                              hipStream_t stream)
{
    const float* X      = (const float*)d_in[0];
    const float* hidden = (const float*)d_in[1];
    const float* asum   = (const float*)d_in[2];
    const float* mask   = (const float*)d_in[3];
    const float* Wh     = (const float*)d_in[4];
    const float* bh     = (const float*)d_in[5];
    const float* Wec    = (const float*)d_in[6];
    const float* bec    = (const float*)d_in[7];
    const float* Wac    = (const float*)d_in[8];
    const float* Waw    = (const float*)d_in[9];
    const float* Wv     = (const float*)d_in[10];
    (void)in_sizes; (void)n_in; (void)out_size; (void)ws_size;

    float* out = (float*)d_out;
    float* ws = (float*)d_ws;
    float* query   = ws;                                    // 16384 floats
    float* energy  = ws + 16384;                            // 32768
    float* emax    = ws + 16384 + 32768;                    // 16 (padded)
    float* alpha_f = emax + 16;                             // 32768
    unsigned short* VTbf = (unsigned short*)(alpha_f + 32768); // 512*832 ushorts

    k_query   <<<dim3(32),      dim3(256),  0, stream>>>(hidden, Wh, bh, bec, query);
    k_build_vt<<<dim3(512),     dim3(128),  0, stream>>>(Wec, Wac, Waw, VTbf);
    k_energy  <<<dim3(16, 32),  dim3(256),  0, stream>>>(X, asum, Wv, query, VTbf, energy);
    k_max     <<<dim3(1),       dim3(1024), 0, stream>>>(energy, emax);
    k_softmax <<<dim3(32),      dim3(1024), 0, stream>>>(energy, emax, mask, asum, alpha_f, out);
    k_context <<<dim3(171, 32), dim3(256),  0, stream>>>(X, alpha_f, out);
}